// Round 12
// baseline (244.050 us; speedup 1.0000x reference)
//
#include <hip/hip_runtime.h>
#include <hip/hip_fp16.h>
#include <math.h>

#define NNODES 100000
#define BSHIFT 7
#define BSIZE 128
#define NBUCK ((NNODES + BSIZE - 1) >> BSHIFT)  // 782
#define SCAT_BLOCKS 512
#define CHUNKCAP 3328        // >= ceil(E/SCAT_BLOCKS) for E<=1.703M
#define CAPSHIFT 12          // 4096 slots per bucket segment
#define BCAP (1 << CAPSHIFT)

// ---------- fused single-pass bucket scatter (bcur pre-zeroed; base folded here) ----------
__global__ __launch_bounds__(256) void k_scatter_fused(const int* __restrict__ src, const int* __restrict__ dst,
                                                       int* __restrict__ bcur, int* __restrict__ staging,
                                                       int E, int chunk) {
    __shared__ int epack[CHUNKCAP];
    __shared__ unsigned short ebuck[CHUNKCAP];
    __shared__ int hist[NBUCK];
    __shared__ int lcur[NBUCK];
    int t = threadIdx.x;
    for (int k = t; k < NBUCK; k += 256) hist[k] = 0;
    __syncthreads();
    int c0 = blockIdx.x * chunk;
    int c1 = min(E, c0 + chunk);
    int n = c1 - c0;
    for (int j = t; j < n; j += 256) {
        int d = dst[c0 + j];
        int s = src[c0 + j];
        int b = d >> BSHIFT;
        epack[j] = (s << BSHIFT) | (d & (BSIZE - 1));
        ebuck[j] = (unsigned short)b;
        atomicAdd(&hist[b], 1);
    }
    __syncthreads();
    for (int k = t; k < NBUCK; k += 256) {
        int c = hist[k];
        int ofs = c ? atomicAdd(&bcur[k], c) : 0;
        lcur[k] = (k << CAPSHIFT) + ofs;
    }
    __syncthreads();
    for (int j = t; j < n; j += 256) {
        int pos = atomicAdd(&lcur[ebuck[j]], 1);
        staging[pos] = epack[j];
    }
}

// ---------- merged: per-bucket CSR + layer-1 transform (same 782-block grid) ----------
__global__ __launch_bounds__(256) void k_csr_transform(const int* __restrict__ staging, const int* __restrict__ bcur,
                                                       int* __restrict__ rowptr, int* __restrict__ rowend,
                                                       int* __restrict__ ssoff, float* __restrict__ dinv,
                                                       const float* __restrict__ X, const float* __restrict__ W,
                                                       __half* __restrict__ Gh, int N) {
    __shared__ float4 Xs[2048];
    __shared__ float dinvs[128];
    __shared__ int lcnt[BSIZE], lpre[BSIZE];
    int b = blockIdx.x, t = threadIdx.x;
    int lane = t & 63;
    int node0 = b << BSHIFT;
    int bbase = b << CAPSHIFT;
    int bend = bbase + bcur[b];
    // ---- CSR phase ----
    if (t < BSIZE) lcnt[t] = 0;
    __syncthreads();
    for (int e = bbase + t; e < bend; e += 256)
        atomicAdd(&lcnt[staging[e] & (BSIZE - 1)], 1);
    __syncthreads();
    if (t < BSIZE) lpre[t] = lcnt[t];
    __syncthreads();
    #pragma unroll
    for (int off = 1; off < BSIZE; off <<= 1) {
        int u = 0;
        if (t < BSIZE && t >= off) u = lpre[t - off];
        __syncthreads();
        if (t < BSIZE) lpre[t] += u;
        __syncthreads();
    }
    if (t < BSIZE) {
        int node = node0 + t;
        float dv = rsqrtf((float)(lcnt[t] + 1));
        dinvs[t] = dv;
        if (node < N) {
            int beg = bbase + lpre[t] - lcnt[t];
            rowptr[node] = beg;
            rowend[node] = beg + lcnt[t];
            dinv[node] = dv;
        }
        lpre[t] -= lcnt[t];
    }
    __syncthreads();
    for (int e = bbase + t; e < bend; e += 256) {
        int p = staging[e];
        int pos = atomicAdd(&lpre[p & (BSIZE - 1)], 1);
        ssoff[bbase + pos] = (p >> BSHIFT) << 7;  // Gh row byte offset
    }
    // ---- transform phase (layer 1) ----
    {
        const float4* X4 = (const float4*)X;
        int lim4 = N << 4;
        int gbase = node0 << 4;
        #pragma unroll
        for (int j = 0; j < 8; j++) {
            int f = j * 256 + t;
            int gi = gbase + f;
            Xs[f] = (gi < lim4) ? X4[gi] : make_float4(0.f, 0.f, 0.f, 0.f);
        }
    }
    float w[64];
    #pragma unroll
    for (int k = 0; k < 64; k++) w[k] = W[k * 64 + lane];
    __syncthreads();
    int woff = (t >> 6) * 32;
    for (int nn = 0; nn < 32; nn += 4) {
        const float4* r0 = &Xs[(woff + nn + 0) * 16];
        const float4* r1 = &Xs[(woff + nn + 1) * 16];
        const float4* r2 = &Xs[(woff + nn + 2) * 16];
        const float4* r3 = &Xs[(woff + nn + 3) * 16];
        float a0 = 0.f, a1 = 0.f, a2 = 0.f, a3 = 0.f;
        #pragma unroll
        for (int kq = 0; kq < 16; kq++) {
            float4 xa = r0[kq];
            float4 xb = r1[kq];
            float4 xc = r2[kq];
            float4 xd = r3[kq];
            a0 = fmaf(xa.x, w[4*kq+0], a0); a0 = fmaf(xa.y, w[4*kq+1], a0);
            a0 = fmaf(xa.z, w[4*kq+2], a0); a0 = fmaf(xa.w, w[4*kq+3], a0);
            a1 = fmaf(xb.x, w[4*kq+0], a1); a1 = fmaf(xb.y, w[4*kq+1], a1);
            a1 = fmaf(xb.z, w[4*kq+2], a1); a1 = fmaf(xb.w, w[4*kq+3], a1);
            a2 = fmaf(xc.x, w[4*kq+0], a2); a2 = fmaf(xc.y, w[4*kq+1], a2);
            a2 = fmaf(xc.z, w[4*kq+2], a2); a2 = fmaf(xc.w, w[4*kq+3], a2);
            a3 = fmaf(xd.x, w[4*kq+0], a3); a3 = fmaf(xd.y, w[4*kq+1], a3);
            a3 = fmaf(xd.z, w[4*kq+2], a3); a3 = fmaf(xd.w, w[4*kq+3], a3);
        }
        int nb = node0 + woff + nn;
        float d0 = dinvs[woff+nn+0], d1 = dinvs[woff+nn+1];
        float d2 = dinvs[woff+nn+2], d3 = dinvs[woff+nn+3];
        if (nb + 3 < N) {
            Gh[(size_t)(nb+0)*64 + lane] = __float2half(a0 * d0);
            Gh[(size_t)(nb+1)*64 + lane] = __float2half(a1 * d1);
            Gh[(size_t)(nb+2)*64 + lane] = __float2half(a2 * d2);
            Gh[(size_t)(nb+3)*64 + lane] = __float2half(a3 * d3);
        } else {
            if (nb+0 < N) Gh[(size_t)(nb+0)*64 + lane] = __float2half(a0 * d0);
            if (nb+1 < N) Gh[(size_t)(nb+1)*64 + lane] = __float2half(a1 * d1);
            if (nb+2 < N) Gh[(size_t)(nb+2)*64 + lane] = __float2half(a2 * d2);
            if (nb+3 < N) Gh[(size_t)(nb+3)*64 + lane] = __float2half(a3 * d3);
        }
    }
}

// ---------- standalone transform (layer 2) ----------
__global__ __launch_bounds__(256) void k_transform3(const float* __restrict__ X, const float* __restrict__ W,
                                                    const float* __restrict__ dinv, __half* __restrict__ Gh, int N) {
    __shared__ float4 Xs[2048];
    __shared__ float dinvs[128];
    int t = threadIdx.x;
    int lane = t & 63;
    int node0 = blockIdx.x << 7;
    {
        const float4* X4 = (const float4*)X;
        int lim4 = N << 4;
        int gbase = node0 << 4;
        #pragma unroll
        for (int j = 0; j < 8; j++) {
            int f = j * 256 + t;
            int gi = gbase + f;
            Xs[f] = (gi < lim4) ? X4[gi] : make_float4(0.f, 0.f, 0.f, 0.f);
        }
    }
    if (t < 128) {
        int nd = node0 + t;
        dinvs[t] = (nd < N) ? dinv[nd] : 0.f;
    }
    float w[64];
    #pragma unroll
    for (int k = 0; k < 64; k++) w[k] = W[k * 64 + lane];
    __syncthreads();
    int woff = (t >> 6) * 32;
    for (int nn = 0; nn < 32; nn += 4) {
        const float4* r0 = &Xs[(woff + nn + 0) * 16];
        const float4* r1 = &Xs[(woff + nn + 1) * 16];
        const float4* r2 = &Xs[(woff + nn + 2) * 16];
        const float4* r3 = &Xs[(woff + nn + 3) * 16];
        float a0 = 0.f, a1 = 0.f, a2 = 0.f, a3 = 0.f;
        #pragma unroll
        for (int kq = 0; kq < 16; kq++) {
            float4 xa = r0[kq];
            float4 xb = r1[kq];
            float4 xc = r2[kq];
            float4 xd = r3[kq];
            a0 = fmaf(xa.x, w[4*kq+0], a0); a0 = fmaf(xa.y, w[4*kq+1], a0);
            a0 = fmaf(xa.z, w[4*kq+2], a0); a0 = fmaf(xa.w, w[4*kq+3], a0);
            a1 = fmaf(xb.x, w[4*kq+0], a1); a1 = fmaf(xb.y, w[4*kq+1], a1);
            a1 = fmaf(xb.z, w[4*kq+2], a1); a1 = fmaf(xb.w, w[4*kq+3], a1);
            a2 = fmaf(xc.x, w[4*kq+0], a2); a2 = fmaf(xc.y, w[4*kq+1], a2);
            a2 = fmaf(xc.z, w[4*kq+2], a2); a2 = fmaf(xc.w, w[4*kq+3], a2);
            a3 = fmaf(xd.x, w[4*kq+0], a3); a3 = fmaf(xd.y, w[4*kq+1], a3);
            a3 = fmaf(xd.z, w[4*kq+2], a3); a3 = fmaf(xd.w, w[4*kq+3], a3);
        }
        int nb = node0 + woff + nn;
        float d0 = dinvs[woff+nn+0], d1 = dinvs[woff+nn+1];
        float d2 = dinvs[woff+nn+2], d3 = dinvs[woff+nn+3];
        if (nb + 3 < N) {
            Gh[(size_t)(nb+0)*64 + lane] = __float2half(a0 * d0);
            Gh[(size_t)(nb+1)*64 + lane] = __float2half(a1 * d1);
            Gh[(size_t)(nb+2)*64 + lane] = __float2half(a2 * d2);
            Gh[(size_t)(nb+3)*64 + lane] = __float2half(a3 * d3);
        } else {
            if (nb+0 < N) Gh[(size_t)(nb+0)*64 + lane] = __float2half(a0 * d0);
            if (nb+1 < N) Gh[(size_t)(nb+1)*64 + lane] = __float2half(a1 * d1);
            if (nb+2 < N) Gh[(size_t)(nb+2)*64 + lane] = __float2half(a2 * d2);
            if (nb+3 < N) Gh[(size_t)(nb+3)*64 + lane] = __float2half(a3 * d3);
        }
    }
}

// ---------- aggregation (+ optional fused FC+softmax) ----------
// wave per node; lane = 8*sub + l; up to 32 edges in flight.
template<bool FC>
__global__ __launch_bounds__(256) void k_agg_t(const __half* __restrict__ G, const int* __restrict__ rowptr,
                                               const int* __restrict__ rowend, const int* __restrict__ ssoff,
                                               const float* __restrict__ dinv, const float* __restrict__ bias,
                                               const float* __restrict__ Wfc, const float* __restrict__ bfc,
                                               float* __restrict__ O, int N) {
    __shared__ float wf[1024];
    __shared__ float wfb[16];
    int t = threadIdx.x;
    if (FC) {
        #pragma unroll
        for (int k = 0; k < 4; k++) wf[k * 256 + t] = Wfc[k * 256 + t];
        if (t < 16) wfb[t] = bfc[t];
        __syncthreads();
    }
    int lane = t & 63;
    int wid = t >> 6;
    int sub = lane >> 3;       // 0..7: edge slot
    int l = lane & 7;          // 0..7: feature octet
    int i = blockIdx.x * 4 + wid;
    if (i >= N) return;
    const char* Gb = (const char*)G;
    int loff = l << 4;
    int beg = rowptr[i], end = rowend[i];
    float a[8] = {0.f, 0.f, 0.f, 0.f, 0.f, 0.f, 0.f, 0.f};
    int e = beg;
    // 32 in flight (4 per sub)
    for (; e + 32 <= end; e += 32) {
        int b0 = e + 4 * sub;
        int o0 = ssoff[b0], o1 = ssoff[b0 + 1], o2 = ssoff[b0 + 2], o3 = ssoff[b0 + 3];
        float4 g0 = *(const float4*)(Gb + o0 + loff);
        float4 g1 = *(const float4*)(Gb + o1 + loff);
        float4 g2 = *(const float4*)(Gb + o2 + loff);
        float4 g3 = *(const float4*)(Gb + o3 + loff);
        const __half2* h0 = (const __half2*)&g0;
        const __half2* h1 = (const __half2*)&g1;
        const __half2* h2 = (const __half2*)&g2;
        const __half2* h3 = (const __half2*)&g3;
        #pragma unroll
        for (int q = 0; q < 4; q++) {
            float2 fA = __half22float2(__hadd2(h0[q], h1[q]));
            float2 fB = __half22float2(__hadd2(h2[q], h3[q]));
            a[2 * q]     += fA.x + fB.x;
            a[2 * q + 1] += fA.y + fB.y;
        }
    }
    if (e + 16 <= end) {  // 2 per sub
        int b0 = e + 2 * sub;
        int o0 = ssoff[b0], o1 = ssoff[b0 + 1];
        float4 g0 = *(const float4*)(Gb + o0 + loff);
        float4 g1 = *(const float4*)(Gb + o1 + loff);
        const __half2* h0 = (const __half2*)&g0;
        const __half2* h1 = (const __half2*)&g1;
        #pragma unroll
        for (int q = 0; q < 4; q++) {
            float2 f = __half22float2(__hadd2(h0[q], h1[q]));
            a[2 * q]     += f.x;
            a[2 * q + 1] += f.y;
        }
        e += 16;
    }
    if (e + 8 <= end) {   // 1 per sub
        int o0 = ssoff[e + sub];
        float4 g0 = *(const float4*)(Gb + o0 + loff);
        const __half2* h0 = (const __half2*)&g0;
        #pragma unroll
        for (int q = 0; q < 4; q++) {
            float2 f = __half22float2(h0[q]);
            a[2 * q]     += f.x;
            a[2 * q + 1] += f.y;
        }
        e += 8;
    }
    if (e + sub < end) {  // tail < 8
        int o0 = ssoff[e + sub];
        float4 g0 = *(const float4*)(Gb + o0 + loff);
        const __half2* h0 = (const __half2*)&g0;
        #pragma unroll
        for (int q = 0; q < 4; q++) {
            float2 f = __half22float2(h0[q]);
            a[2 * q]     += f.x;
            a[2 * q + 1] += f.y;
        }
    }
    #pragma unroll
    for (int mask = 8; mask <= 32; mask <<= 1) {
        #pragma unroll
        for (int q = 0; q < 8; q++) a[q] += __shfl_xor(a[q], mask);
    }
    // epilogue: self + bias + relu (all lanes; uniform per l-group)
    float4 gs = *(const float4*)(Gb + (i << 7) + loff);
    const __half2* hs = (const __half2*)&gs;
    float di = dinv[i];
    float4 b0v = *(const float4*)(bias + 8 * l);
    float4 b1v = *(const float4*)(bias + 8 * l + 4);
    float bb[8] = {b0v.x, b0v.y, b0v.z, b0v.w, b1v.x, b1v.y, b1v.z, b1v.w};
    float r[8];
    #pragma unroll
    for (int q = 0; q < 4; q++) {
        float2 fs = __half22float2(hs[q]);
        r[2 * q]     = fmaxf(fmaf(di, a[2 * q] + fs.x, bb[2 * q]), 0.f);
        r[2 * q + 1] = fmaxf(fmaf(di, a[2 * q + 1] + fs.y, bb[2 * q + 1]), 0.f);
    }
    if (!FC) {
        if (sub == 0) {
            *(float4*)(O + (size_t)i * 64 + 8 * l)     = make_float4(r[0], r[1], r[2], r[3]);
            *(float4*)(O + (size_t)i * 64 + 8 * l + 4) = make_float4(r[4], r[5], r[6], r[7]);
        }
    } else {
        // FC: sub computes classes 2*sub, 2*sub+1 over its 8 features, reduce over l
        int c0 = 2 * sub;
        float p0 = 0.f, p1 = 0.f;
        #pragma unroll
        for (int q = 0; q < 8; q++) {
            int f = 8 * l + q;
            p0 = fmaf(r[q], wf[f * 16 + c0], p0);
            p1 = fmaf(r[q], wf[f * 16 + c0 + 1], p1);
        }
        #pragma unroll
        for (int mask = 1; mask <= 4; mask <<= 1) {
            p0 += __shfl_xor(p0, mask);
            p1 += __shfl_xor(p1, mask);
        }
        p0 += wfb[c0];
        p1 += wfb[c0 + 1];
        // softmax over the 16 logits spread across subs
        float mx = fmaxf(p0, p1);
        #pragma unroll
        for (int mask = 8; mask <= 32; mask <<= 1) mx = fmaxf(mx, __shfl_xor(mx, mask));
        float e0 = expf(p0 - mx), e1 = expf(p1 - mx);
        float ssum = e0 + e1;
        #pragma unroll
        for (int mask = 8; mask <= 32; mask <<= 1) ssum += __shfl_xor(ssum, mask);
        if (l == 0) {
            float inv = 1.0f / ssum;
            *(float2*)(O + (size_t)i * 16 + c0) = make_float2(e0 * inv, e1 * inv);
        }
    }
}

extern "C" void kernel_launch(void* const* d_in, const int* in_sizes, int n_in,
                              void* d_out, int out_size, void* d_ws, size_t ws_size,
                              hipStream_t stream) {
    const float* x   = (const float*)d_in[0];
    const int*   ei  = (const int*)d_in[1];
    const float* W1  = (const float*)d_in[2];
    const float* b1  = (const float*)d_in[3];
    const float* W2  = (const float*)d_in[4];
    const float* b2  = (const float*)d_in[5];
    const float* Wfc = (const float*)d_in[6];
    const float* bfc = (const float*)d_in[7];
    float* out = (float*)d_out;
    const int N = NNODES;
    const int E = in_sizes[1] / 2;

    char* ws = (char*)d_ws;
    size_t off = 0;
    auto take = [&](size_t bytes) {
        char* p = ws + off;
        off = (off + bytes + 255) & ~(size_t)255;
        return p;
    };
    int*    staging = (int*)take((size_t)NBUCK * BCAP * 4);
    int*    ssoff   = (int*)take((size_t)NBUCK * BCAP * 4);
    float*  bufB    = (float*)take((size_t)N * 64 * 4);
    __half* Gh      = (__half*)take((size_t)N * 64 * 2);
    int*    rowptr  = (int*)take((size_t)N * 4);
    int*    rowend  = (int*)take((size_t)N * 4);
    float*  dinv    = (float*)take((size_t)N * 4);
    int*    bcur    = (int*)take((size_t)NBUCK * 4);

    const int* e_src = ei;
    const int* e_dst = ei + E;

    int chunk = (E + SCAT_BLOCKS - 1) / SCAT_BLOCKS;
    hipMemsetAsync(bcur, 0, (size_t)NBUCK * 4, stream);
    k_scatter_fused<<<SCAT_BLOCKS, 256, 0, stream>>>(e_src, e_dst, bcur, staging, E, chunk);
    k_csr_transform<<<NBUCK, 256, 0, stream>>>(staging, bcur, rowptr, rowend, ssoff, dinv, x, W1, Gh, N);
    k_agg_t<false><<<(N + 3) / 4, 256, 0, stream>>>(Gh, rowptr, rowend, ssoff, dinv, b1,
                                                    nullptr, nullptr, bufB, N);
    k_transform3<<<(N + 127) / 128, 256, 0, stream>>>(bufB, W2, dinv, Gh, N);
    k_agg_t<true><<<(N + 3) / 4, 256, 0, stream>>>(Gh, rowptr, rowend, ssoff, dinv, b2,
                                                   Wfc, bfc, out, N);
}

// Round 13
// 219.186 us; speedup vs baseline: 1.1134x; 1.1134x over previous
//
#include <hip/hip_runtime.h>
#include <hip/hip_fp16.h>
#include <math.h>

#define NNODES 100000
#define BSHIFT 7
#define BSIZE 128
#define NBUCK ((NNODES + BSIZE - 1) >> BSHIFT)  // 782
#define SCAT_BLOCKS 512
#define CHUNKCAP 3328        // >= ceil(E/SCAT_BLOCKS) for E<=1.703M
#define CAPSHIFT 12          // 4096 slots per bucket segment
#define BCAP (1 << CAPSHIFT)

// ---------- fused single-pass bucket scatter (bcur pre-zeroed; base folded here) ----------
__global__ __launch_bounds__(256) void k_scatter_fused(const int* __restrict__ src, const int* __restrict__ dst,
                                                       int* __restrict__ bcur, int* __restrict__ staging,
                                                       int E, int chunk) {
    __shared__ int epack[CHUNKCAP];
    __shared__ unsigned short ebuck[CHUNKCAP];
    __shared__ int hist[NBUCK];
    __shared__ int lcur[NBUCK];
    int t = threadIdx.x;
    for (int k = t; k < NBUCK; k += 256) hist[k] = 0;
    __syncthreads();
    int c0 = blockIdx.x * chunk;
    int c1 = min(E, c0 + chunk);
    int n = c1 - c0;
    for (int j = t; j < n; j += 256) {
        int d = dst[c0 + j];
        int s = src[c0 + j];
        int b = d >> BSHIFT;
        epack[j] = (s << BSHIFT) | (d & (BSIZE - 1));
        ebuck[j] = (unsigned short)b;
        atomicAdd(&hist[b], 1);
    }
    __syncthreads();
    for (int k = t; k < NBUCK; k += 256) {
        int c = hist[k];
        int ofs = c ? atomicAdd(&bcur[k], c) : 0;
        lcur[k] = (k << CAPSHIFT) + ofs;
    }
    __syncthreads();
    for (int j = t; j < n; j += 256) {
        int pos = atomicAdd(&lcur[ebuck[j]], 1);
        staging[pos] = epack[j];
    }
}

// ---------- merged: per-bucket CSR + layer-1 transform (same 782-block grid) ----------
__global__ __launch_bounds__(256) void k_csr_transform(const int* __restrict__ staging, const int* __restrict__ bcur,
                                                       int* __restrict__ rowptr, int* __restrict__ rowend,
                                                       int* __restrict__ ssoff, float* __restrict__ dinv,
                                                       const float* __restrict__ X, const float* __restrict__ W,
                                                       __half* __restrict__ Gh, int N) {
    __shared__ float4 Xs[2048];
    __shared__ float dinvs[128];
    __shared__ int lcnt[BSIZE], lpre[BSIZE];
    int b = blockIdx.x, t = threadIdx.x;
    int lane = t & 63;
    int node0 = b << BSHIFT;
    int bbase = b << CAPSHIFT;
    int bend = bbase + bcur[b];
    // ---- CSR phase ----
    if (t < BSIZE) lcnt[t] = 0;
    __syncthreads();
    for (int e = bbase + t; e < bend; e += 256)
        atomicAdd(&lcnt[staging[e] & (BSIZE - 1)], 1);
    __syncthreads();
    if (t < BSIZE) lpre[t] = lcnt[t];
    __syncthreads();
    #pragma unroll
    for (int off = 1; off < BSIZE; off <<= 1) {
        int u = 0;
        if (t < BSIZE && t >= off) u = lpre[t - off];
        __syncthreads();
        if (t < BSIZE) lpre[t] += u;
        __syncthreads();
    }
    if (t < BSIZE) {
        int node = node0 + t;
        float dv = rsqrtf((float)(lcnt[t] + 1));
        dinvs[t] = dv;
        if (node < N) {
            int beg = bbase + lpre[t] - lcnt[t];
            rowptr[node] = beg;
            rowend[node] = beg + lcnt[t];
            dinv[node] = dv;
        }
        lpre[t] -= lcnt[t];
    }
    __syncthreads();
    for (int e = bbase + t; e < bend; e += 256) {
        int p = staging[e];
        int pos = atomicAdd(&lpre[p & (BSIZE - 1)], 1);
        ssoff[bbase + pos] = (p >> BSHIFT) << 7;  // Gh row byte offset
    }
    // ---- transform phase (layer 1) ----
    {
        const float4* X4 = (const float4*)X;
        int lim4 = N << 4;
        int gbase = node0 << 4;
        #pragma unroll
        for (int j = 0; j < 8; j++) {
            int f = j * 256 + t;
            int gi = gbase + f;
            Xs[f] = (gi < lim4) ? X4[gi] : make_float4(0.f, 0.f, 0.f, 0.f);
        }
    }
    float w[64];
    #pragma unroll
    for (int k = 0; k < 64; k++) w[k] = W[k * 64 + lane];
    __syncthreads();
    int woff = (t >> 6) * 32;
    for (int nn = 0; nn < 32; nn += 4) {
        const float4* r0 = &Xs[(woff + nn + 0) * 16];
        const float4* r1 = &Xs[(woff + nn + 1) * 16];
        const float4* r2 = &Xs[(woff + nn + 2) * 16];
        const float4* r3 = &Xs[(woff + nn + 3) * 16];
        float a0 = 0.f, a1 = 0.f, a2 = 0.f, a3 = 0.f;
        #pragma unroll
        for (int kq = 0; kq < 16; kq++) {
            float4 xa = r0[kq];
            float4 xb = r1[kq];
            float4 xc = r2[kq];
            float4 xd = r3[kq];
            a0 = fmaf(xa.x, w[4*kq+0], a0); a0 = fmaf(xa.y, w[4*kq+1], a0);
            a0 = fmaf(xa.z, w[4*kq+2], a0); a0 = fmaf(xa.w, w[4*kq+3], a0);
            a1 = fmaf(xb.x, w[4*kq+0], a1); a1 = fmaf(xb.y, w[4*kq+1], a1);
            a1 = fmaf(xb.z, w[4*kq+2], a1); a1 = fmaf(xb.w, w[4*kq+3], a1);
            a2 = fmaf(xc.x, w[4*kq+0], a2); a2 = fmaf(xc.y, w[4*kq+1], a2);
            a2 = fmaf(xc.z, w[4*kq+2], a2); a2 = fmaf(xc.w, w[4*kq+3], a2);
            a3 = fmaf(xd.x, w[4*kq+0], a3); a3 = fmaf(xd.y, w[4*kq+1], a3);
            a3 = fmaf(xd.z, w[4*kq+2], a3); a3 = fmaf(xd.w, w[4*kq+3], a3);
        }
        int nb = node0 + woff + nn;
        float d0 = dinvs[woff+nn+0], d1 = dinvs[woff+nn+1];
        float d2 = dinvs[woff+nn+2], d3 = dinvs[woff+nn+3];
        if (nb + 3 < N) {
            Gh[(size_t)(nb+0)*64 + lane] = __float2half(a0 * d0);
            Gh[(size_t)(nb+1)*64 + lane] = __float2half(a1 * d1);
            Gh[(size_t)(nb+2)*64 + lane] = __float2half(a2 * d2);
            Gh[(size_t)(nb+3)*64 + lane] = __float2half(a3 * d3);
        } else {
            if (nb+0 < N) Gh[(size_t)(nb+0)*64 + lane] = __float2half(a0 * d0);
            if (nb+1 < N) Gh[(size_t)(nb+1)*64 + lane] = __float2half(a1 * d1);
            if (nb+2 < N) Gh[(size_t)(nb+2)*64 + lane] = __float2half(a2 * d2);
            if (nb+3 < N) Gh[(size_t)(nb+3)*64 + lane] = __float2half(a3 * d3);
        }
    }
}

// ---------- standalone transform (layer 2) ----------
__global__ __launch_bounds__(256) void k_transform3(const float* __restrict__ X, const float* __restrict__ W,
                                                    const float* __restrict__ dinv, __half* __restrict__ Gh, int N) {
    __shared__ float4 Xs[2048];
    __shared__ float dinvs[128];
    int t = threadIdx.x;
    int lane = t & 63;
    int node0 = blockIdx.x << 7;
    {
        const float4* X4 = (const float4*)X;
        int lim4 = N << 4;
        int gbase = node0 << 4;
        #pragma unroll
        for (int j = 0; j < 8; j++) {
            int f = j * 256 + t;
            int gi = gbase + f;
            Xs[f] = (gi < lim4) ? X4[gi] : make_float4(0.f, 0.f, 0.f, 0.f);
        }
    }
    if (t < 128) {
        int nd = node0 + t;
        dinvs[t] = (nd < N) ? dinv[nd] : 0.f;
    }
    float w[64];
    #pragma unroll
    for (int k = 0; k < 64; k++) w[k] = W[k * 64 + lane];
    __syncthreads();
    int woff = (t >> 6) * 32;
    for (int nn = 0; nn < 32; nn += 4) {
        const float4* r0 = &Xs[(woff + nn + 0) * 16];
        const float4* r1 = &Xs[(woff + nn + 1) * 16];
        const float4* r2 = &Xs[(woff + nn + 2) * 16];
        const float4* r3 = &Xs[(woff + nn + 3) * 16];
        float a0 = 0.f, a1 = 0.f, a2 = 0.f, a3 = 0.f;
        #pragma unroll
        for (int kq = 0; kq < 16; kq++) {
            float4 xa = r0[kq];
            float4 xb = r1[kq];
            float4 xc = r2[kq];
            float4 xd = r3[kq];
            a0 = fmaf(xa.x, w[4*kq+0], a0); a0 = fmaf(xa.y, w[4*kq+1], a0);
            a0 = fmaf(xa.z, w[4*kq+2], a0); a0 = fmaf(xa.w, w[4*kq+3], a0);
            a1 = fmaf(xb.x, w[4*kq+0], a1); a1 = fmaf(xb.y, w[4*kq+1], a1);
            a1 = fmaf(xb.z, w[4*kq+2], a1); a1 = fmaf(xb.w, w[4*kq+3], a1);
            a2 = fmaf(xc.x, w[4*kq+0], a2); a2 = fmaf(xc.y, w[4*kq+1], a2);
            a2 = fmaf(xc.z, w[4*kq+2], a2); a2 = fmaf(xc.w, w[4*kq+3], a2);
            a3 = fmaf(xd.x, w[4*kq+0], a3); a3 = fmaf(xd.y, w[4*kq+1], a3);
            a3 = fmaf(xd.z, w[4*kq+2], a3); a3 = fmaf(xd.w, w[4*kq+3], a3);
        }
        int nb = node0 + woff + nn;
        float d0 = dinvs[woff+nn+0], d1 = dinvs[woff+nn+1];
        float d2 = dinvs[woff+nn+2], d3 = dinvs[woff+nn+3];
        if (nb + 3 < N) {
            Gh[(size_t)(nb+0)*64 + lane] = __float2half(a0 * d0);
            Gh[(size_t)(nb+1)*64 + lane] = __float2half(a1 * d1);
            Gh[(size_t)(nb+2)*64 + lane] = __float2half(a2 * d2);
            Gh[(size_t)(nb+3)*64 + lane] = __float2half(a3 * d3);
        } else {
            if (nb+0 < N) Gh[(size_t)(nb+0)*64 + lane] = __float2half(a0 * d0);
            if (nb+1 < N) Gh[(size_t)(nb+1)*64 + lane] = __float2half(a1 * d1);
            if (nb+2 < N) Gh[(size_t)(nb+2)*64 + lane] = __float2half(a2 * d2);
            if (nb+3 < N) Gh[(size_t)(nb+3)*64 + lane] = __float2half(a3 * d3);
        }
    }
}

// ---------- aggregation (+ optional fused FC+softmax) ----------
// wave per node; lane = 8*sub + l; 16 edges in flight (R11-measured loop).
// FC weights in LDS at stride 17: bank = (8l+17q+2sub)%32 -> max 2-way (free).
template<bool FC>
__global__ __launch_bounds__(256) void k_agg_t(const __half* __restrict__ G, const int* __restrict__ rowptr,
                                               const int* __restrict__ rowend, const int* __restrict__ ssoff,
                                               const float* __restrict__ dinv, const float* __restrict__ bias,
                                               const float* __restrict__ Wfc, const float* __restrict__ bfc,
                                               float* __restrict__ O, int N) {
    __shared__ float wfs[64 * 17];
    __shared__ float wfb[16];
    int t = threadIdx.x;
    if (FC) {
        #pragma unroll
        for (int k = 0; k < 4; k++) {
            int idx = k * 256 + t;
            wfs[(idx >> 4) * 17 + (idx & 15)] = Wfc[idx];
        }
        if (t < 16) wfb[t] = bfc[t];
        __syncthreads();
    }
    int lane = t & 63;
    int wid = t >> 6;
    int sub = lane >> 3;       // 0..7: edge slot
    int l = lane & 7;          // 0..7: feature octet
    int i = blockIdx.x * 4 + wid;
    if (i >= N) return;
    const char* Gb = (const char*)G;
    int loff = l << 4;
    int beg = rowptr[i], end = rowend[i];
    float a[8] = {0.f, 0.f, 0.f, 0.f, 0.f, 0.f, 0.f, 0.f};
    int e = beg + sub;
    // 16 edges in flight (2 per sub), fp16 pair pre-sum then f32 accumulate
    for (; e + 8 < end; e += 16) {
        int o0 = ssoff[e];
        int o1 = ssoff[e + 8];
        float4 g0 = *(const float4*)(Gb + o0 + loff);
        float4 g1 = *(const float4*)(Gb + o1 + loff);
        const __half2* h0 = (const __half2*)&g0;
        const __half2* h1 = (const __half2*)&g1;
        #pragma unroll
        for (int q = 0; q < 4; q++) {
            float2 f = __half22float2(__hadd2(h0[q], h1[q]));
            a[2 * q]     += f.x;
            a[2 * q + 1] += f.y;
        }
    }
    if (e < end) {
        int o0 = ssoff[e];
        float4 g0 = *(const float4*)(Gb + o0 + loff);
        const __half2* h0 = (const __half2*)&g0;
        #pragma unroll
        for (int q = 0; q < 4; q++) {
            float2 f = __half22float2(h0[q]);
            a[2 * q]     += f.x;
            a[2 * q + 1] += f.y;
        }
    }
    #pragma unroll
    for (int mask = 8; mask <= 32; mask <<= 1) {
        #pragma unroll
        for (int q = 0; q < 8; q++) a[q] += __shfl_xor(a[q], mask);
    }
    // epilogue: self + bias + relu
    float4 gs = *(const float4*)(Gb + (i << 7) + loff);
    const __half2* hs = (const __half2*)&gs;
    float di = dinv[i];
    float4 b0v = *(const float4*)(bias + 8 * l);
    float4 b1v = *(const float4*)(bias + 8 * l + 4);
    float bb[8] = {b0v.x, b0v.y, b0v.z, b0v.w, b1v.x, b1v.y, b1v.z, b1v.w};
    float r[8];
    #pragma unroll
    for (int q = 0; q < 4; q++) {
        float2 fs = __half22float2(hs[q]);
        r[2 * q]     = fmaxf(fmaf(di, a[2 * q] + fs.x, bb[2 * q]), 0.f);
        r[2 * q + 1] = fmaxf(fmaf(di, a[2 * q + 1] + fs.y, bb[2 * q + 1]), 0.f);
    }
    if (!FC) {
        if (sub == 0) {
            *(float4*)(O + (size_t)i * 64 + 8 * l)     = make_float4(r[0], r[1], r[2], r[3]);
            *(float4*)(O + (size_t)i * 64 + 8 * l + 4) = make_float4(r[4], r[5], r[6], r[7]);
        }
    } else {
        // FC: sub computes classes 2*sub, 2*sub+1 over its 8 features, reduce over l
        int c0 = 2 * sub;
        float p0 = 0.f, p1 = 0.f;
        #pragma unroll
        for (int q = 0; q < 8; q++) {
            int fi = (8 * l + q) * 17;
            p0 = fmaf(r[q], wfs[fi + c0], p0);
            p1 = fmaf(r[q], wfs[fi + c0 + 1], p1);
        }
        #pragma unroll
        for (int mask = 1; mask <= 4; mask <<= 1) {
            p0 += __shfl_xor(p0, mask);
            p1 += __shfl_xor(p1, mask);
        }
        p0 += wfb[c0];
        p1 += wfb[c0 + 1];
        float mx = fmaxf(p0, p1);
        #pragma unroll
        for (int mask = 8; mask <= 32; mask <<= 1) mx = fmaxf(mx, __shfl_xor(mx, mask));
        float e0 = expf(p0 - mx), e1 = expf(p1 - mx);
        float ssum = e0 + e1;
        #pragma unroll
        for (int mask = 8; mask <= 32; mask <<= 1) ssum += __shfl_xor(ssum, mask);
        if (l == 0) {
            float inv = 1.0f / ssum;
            *(float2*)(O + (size_t)i * 16 + c0) = make_float2(e0 * inv, e1 * inv);
        }
    }
}

extern "C" void kernel_launch(void* const* d_in, const int* in_sizes, int n_in,
                              void* d_out, int out_size, void* d_ws, size_t ws_size,
                              hipStream_t stream) {
    const float* x   = (const float*)d_in[0];
    const int*   ei  = (const int*)d_in[1];
    const float* W1  = (const float*)d_in[2];
    const float* b1  = (const float*)d_in[3];
    const float* W2  = (const float*)d_in[4];
    const float* b2  = (const float*)d_in[5];
    const float* Wfc = (const float*)d_in[6];
    const float* bfc = (const float*)d_in[7];
    float* out = (float*)d_out;
    const int N = NNODES;
    const int E = in_sizes[1] / 2;

    char* ws = (char*)d_ws;
    size_t off = 0;
    auto take = [&](size_t bytes) {
        char* p = ws + off;
        off = (off + bytes + 255) & ~(size_t)255;
        return p;
    };
    int*    staging = (int*)take((size_t)NBUCK * BCAP * 4);
    int*    ssoff   = (int*)take((size_t)NBUCK * BCAP * 4);
    float*  bufB    = (float*)take((size_t)N * 64 * 4);
    __half* Gh      = (__half*)take((size_t)N * 64 * 2);
    int*    rowptr  = (int*)take((size_t)N * 4);
    int*    rowend  = (int*)take((size_t)N * 4);
    float*  dinv    = (float*)take((size_t)N * 4);
    int*    bcur    = (int*)take((size_t)NBUCK * 4);

    const int* e_src = ei;
    const int* e_dst = ei + E;

    int chunk = (E + SCAT_BLOCKS - 1) / SCAT_BLOCKS;
    hipMemsetAsync(bcur, 0, (size_t)NBUCK * 4, stream);
    k_scatter_fused<<<SCAT_BLOCKS, 256, 0, stream>>>(e_src, e_dst, bcur, staging, E, chunk);
    k_csr_transform<<<NBUCK, 256, 0, stream>>>(staging, bcur, rowptr, rowend, ssoff, dinv, x, W1, Gh, N);
    k_agg_t<false><<<(N + 3) / 4, 256, 0, stream>>>(Gh, rowptr, rowend, ssoff, dinv, b1,
                                                    nullptr, nullptr, bufB, N);
    k_transform3<<<(N + 127) / 128, 256, 0, stream>>>(bufB, W2, dinv, Gh, N);
    k_agg_t<true><<<(N + 3) / 4, 256, 0, stream>>>(Gh, rowptr, rowend, ssoff, dinv, b2,
                                                   Wfc, bfc, out, N);
}

// Round 14
// 212.532 us; speedup vs baseline: 1.1483x; 1.0313x over previous
//
#include <hip/hip_runtime.h>
#include <hip/hip_fp16.h>
#include <math.h>

#define NNODES 100000
#define BSHIFT 7
#define BSIZE 128
#define NBUCK ((NNODES + BSIZE - 1) >> BSHIFT)  // 782
#define SCAT_BLOCKS 512
#define CHUNKCAP 3328        // >= ceil(E/SCAT_BLOCKS) for E<=1.703M
#define CAPSHIFT 12          // 4096 slots per bucket segment
#define BCAP (1 << CAPSHIFT)

// ---------- fused single-pass bucket scatter (bcur pre-zeroed; base folded here) ----------
__global__ __launch_bounds__(256) void k_scatter_fused(const int* __restrict__ src, const int* __restrict__ dst,
                                                       int* __restrict__ bcur, int* __restrict__ staging,
                                                       int E, int chunk) {
    __shared__ int epack[CHUNKCAP];
    __shared__ unsigned short ebuck[CHUNKCAP];
    __shared__ int hist[NBUCK];
    __shared__ int lcur[NBUCK];
    int t = threadIdx.x;
    for (int k = t; k < NBUCK; k += 256) hist[k] = 0;
    __syncthreads();
    int c0 = blockIdx.x * chunk;
    int c1 = min(E, c0 + chunk);
    int n = c1 - c0;
    for (int j = t; j < n; j += 256) {
        int d = dst[c0 + j];
        int s = src[c0 + j];
        int b = d >> BSHIFT;
        epack[j] = (s << BSHIFT) | (d & (BSIZE - 1));
        ebuck[j] = (unsigned short)b;
        atomicAdd(&hist[b], 1);
    }
    __syncthreads();
    for (int k = t; k < NBUCK; k += 256) {
        int c = hist[k];
        int ofs = c ? atomicAdd(&bcur[k], c) : 0;
        lcur[k] = (k << CAPSHIFT) + ofs;
    }
    __syncthreads();
    for (int j = t; j < n; j += 256) {
        int pos = atomicAdd(&lcur[ebuck[j]], 1);
        staging[pos] = epack[j];
    }
}

// ---------- merged: per-bucket CSR + layer-1 transform (same 782-block grid) ----------
__global__ __launch_bounds__(256) void k_csr_transform(const int* __restrict__ staging, const int* __restrict__ bcur,
                                                       int* __restrict__ rowptr, int* __restrict__ rowend,
                                                       int* __restrict__ ssoff, float* __restrict__ dinv,
                                                       const float* __restrict__ X, const float* __restrict__ W,
                                                       __half* __restrict__ Gh, int N) {
    __shared__ float4 Xs[2048];
    __shared__ float dinvs[128];
    __shared__ int lcnt[BSIZE], lpre[BSIZE];
    int b = blockIdx.x, t = threadIdx.x;
    int lane = t & 63;
    int node0 = b << BSHIFT;
    int bbase = b << CAPSHIFT;
    int bend = bbase + bcur[b];
    // ---- CSR phase ----
    if (t < BSIZE) lcnt[t] = 0;
    __syncthreads();
    for (int e = bbase + t; e < bend; e += 256)
        atomicAdd(&lcnt[staging[e] & (BSIZE - 1)], 1);
    __syncthreads();
    if (t < BSIZE) lpre[t] = lcnt[t];
    __syncthreads();
    #pragma unroll
    for (int off = 1; off < BSIZE; off <<= 1) {
        int u = 0;
        if (t < BSIZE && t >= off) u = lpre[t - off];
        __syncthreads();
        if (t < BSIZE) lpre[t] += u;
        __syncthreads();
    }
    if (t < BSIZE) {
        int node = node0 + t;
        float dv = rsqrtf((float)(lcnt[t] + 1));
        dinvs[t] = dv;
        if (node < N) {
            int beg = bbase + lpre[t] - lcnt[t];
            rowptr[node] = beg;
            rowend[node] = beg + lcnt[t];
            dinv[node] = dv;
        }
        lpre[t] -= lcnt[t];
    }
    __syncthreads();
    for (int e = bbase + t; e < bend; e += 256) {
        int p = staging[e];
        int pos = atomicAdd(&lpre[p & (BSIZE - 1)], 1);
        ssoff[bbase + pos] = (p >> BSHIFT) << 7;  // Gh row byte offset
    }
    // ---- transform phase (layer 1) ----
    {
        const float4* X4 = (const float4*)X;
        int lim4 = N << 4;
        int gbase = node0 << 4;
        #pragma unroll
        for (int j = 0; j < 8; j++) {
            int f = j * 256 + t;
            int gi = gbase + f;
            Xs[f] = (gi < lim4) ? X4[gi] : make_float4(0.f, 0.f, 0.f, 0.f);
        }
    }
    float w[64];
    #pragma unroll
    for (int k = 0; k < 64; k++) w[k] = W[k * 64 + lane];
    __syncthreads();
    int woff = (t >> 6) * 32;
    for (int nn = 0; nn < 32; nn += 4) {
        const float4* r0 = &Xs[(woff + nn + 0) * 16];
        const float4* r1 = &Xs[(woff + nn + 1) * 16];
        const float4* r2 = &Xs[(woff + nn + 2) * 16];
        const float4* r3 = &Xs[(woff + nn + 3) * 16];
        float a0 = 0.f, a1 = 0.f, a2 = 0.f, a3 = 0.f;
        #pragma unroll
        for (int kq = 0; kq < 16; kq++) {
            float4 xa = r0[kq];
            float4 xb = r1[kq];
            float4 xc = r2[kq];
            float4 xd = r3[kq];
            a0 = fmaf(xa.x, w[4*kq+0], a0); a0 = fmaf(xa.y, w[4*kq+1], a0);
            a0 = fmaf(xa.z, w[4*kq+2], a0); a0 = fmaf(xa.w, w[4*kq+3], a0);
            a1 = fmaf(xb.x, w[4*kq+0], a1); a1 = fmaf(xb.y, w[4*kq+1], a1);
            a1 = fmaf(xb.z, w[4*kq+2], a1); a1 = fmaf(xb.w, w[4*kq+3], a1);
            a2 = fmaf(xc.x, w[4*kq+0], a2); a2 = fmaf(xc.y, w[4*kq+1], a2);
            a2 = fmaf(xc.z, w[4*kq+2], a2); a2 = fmaf(xc.w, w[4*kq+3], a2);
            a3 = fmaf(xd.x, w[4*kq+0], a3); a3 = fmaf(xd.y, w[4*kq+1], a3);
            a3 = fmaf(xd.z, w[4*kq+2], a3); a3 = fmaf(xd.w, w[4*kq+3], a3);
        }
        int nb = node0 + woff + nn;
        float d0 = dinvs[woff+nn+0], d1 = dinvs[woff+nn+1];
        float d2 = dinvs[woff+nn+2], d3 = dinvs[woff+nn+3];
        if (nb + 3 < N) {
            Gh[(size_t)(nb+0)*64 + lane] = __float2half(a0 * d0);
            Gh[(size_t)(nb+1)*64 + lane] = __float2half(a1 * d1);
            Gh[(size_t)(nb+2)*64 + lane] = __float2half(a2 * d2);
            Gh[(size_t)(nb+3)*64 + lane] = __float2half(a3 * d3);
        } else {
            if (nb+0 < N) Gh[(size_t)(nb+0)*64 + lane] = __float2half(a0 * d0);
            if (nb+1 < N) Gh[(size_t)(nb+1)*64 + lane] = __float2half(a1 * d1);
            if (nb+2 < N) Gh[(size_t)(nb+2)*64 + lane] = __float2half(a2 * d2);
            if (nb+3 < N) Gh[(size_t)(nb+3)*64 + lane] = __float2half(a3 * d3);
        }
    }
}

// ---------- standalone transform (layer 2) ----------
__global__ __launch_bounds__(256) void k_transform3(const float* __restrict__ X, const float* __restrict__ W,
                                                    const float* __restrict__ dinv, __half* __restrict__ Gh, int N) {
    __shared__ float4 Xs[2048];
    __shared__ float dinvs[128];
    int t = threadIdx.x;
    int lane = t & 63;
    int node0 = blockIdx.x << 7;
    {
        const float4* X4 = (const float4*)X;
        int lim4 = N << 4;
        int gbase = node0 << 4;
        #pragma unroll
        for (int j = 0; j < 8; j++) {
            int f = j * 256 + t;
            int gi = gbase + f;
            Xs[f] = (gi < lim4) ? X4[gi] : make_float4(0.f, 0.f, 0.f, 0.f);
        }
    }
    if (t < 128) {
        int nd = node0 + t;
        dinvs[t] = (nd < N) ? dinv[nd] : 0.f;
    }
    float w[64];
    #pragma unroll
    for (int k = 0; k < 64; k++) w[k] = W[k * 64 + lane];
    __syncthreads();
    int woff = (t >> 6) * 32;
    for (int nn = 0; nn < 32; nn += 4) {
        const float4* r0 = &Xs[(woff + nn + 0) * 16];
        const float4* r1 = &Xs[(woff + nn + 1) * 16];
        const float4* r2 = &Xs[(woff + nn + 2) * 16];
        const float4* r3 = &Xs[(woff + nn + 3) * 16];
        float a0 = 0.f, a1 = 0.f, a2 = 0.f, a3 = 0.f;
        #pragma unroll
        for (int kq = 0; kq < 16; kq++) {
            float4 xa = r0[kq];
            float4 xb = r1[kq];
            float4 xc = r2[kq];
            float4 xd = r3[kq];
            a0 = fmaf(xa.x, w[4*kq+0], a0); a0 = fmaf(xa.y, w[4*kq+1], a0);
            a0 = fmaf(xa.z, w[4*kq+2], a0); a0 = fmaf(xa.w, w[4*kq+3], a0);
            a1 = fmaf(xb.x, w[4*kq+0], a1); a1 = fmaf(xb.y, w[4*kq+1], a1);
            a1 = fmaf(xb.z, w[4*kq+2], a1); a1 = fmaf(xb.w, w[4*kq+3], a1);
            a2 = fmaf(xc.x, w[4*kq+0], a2); a2 = fmaf(xc.y, w[4*kq+1], a2);
            a2 = fmaf(xc.z, w[4*kq+2], a2); a2 = fmaf(xc.w, w[4*kq+3], a2);
            a3 = fmaf(xd.x, w[4*kq+0], a3); a3 = fmaf(xd.y, w[4*kq+1], a3);
            a3 = fmaf(xd.z, w[4*kq+2], a3); a3 = fmaf(xd.w, w[4*kq+3], a3);
        }
        int nb = node0 + woff + nn;
        float d0 = dinvs[woff+nn+0], d1 = dinvs[woff+nn+1];
        float d2 = dinvs[woff+nn+2], d3 = dinvs[woff+nn+3];
        if (nb + 3 < N) {
            Gh[(size_t)(nb+0)*64 + lane] = __float2half(a0 * d0);
            Gh[(size_t)(nb+1)*64 + lane] = __float2half(a1 * d1);
            Gh[(size_t)(nb+2)*64 + lane] = __float2half(a2 * d2);
            Gh[(size_t)(nb+3)*64 + lane] = __float2half(a3 * d3);
        } else {
            if (nb+0 < N) Gh[(size_t)(nb+0)*64 + lane] = __float2half(a0 * d0);
            if (nb+1 < N) Gh[(size_t)(nb+1)*64 + lane] = __float2half(a1 * d1);
            if (nb+2 < N) Gh[(size_t)(nb+2)*64 + lane] = __float2half(a2 * d2);
            if (nb+3 < N) Gh[(size_t)(nb+3)*64 + lane] = __float2half(a3 * d3);
        }
    }
}

// ---------- out = relu(dinv[i] * (G[i] + sum_j G[j]) + b), G fp16, byte-offset edges ----------
// wave per node; lane = 8*sub + l; 16 edges in flight (measured-best loop).
__global__ __launch_bounds__(256) void k_agg(const __half* __restrict__ G, const int* __restrict__ rowptr,
                                             const int* __restrict__ rowend, const int* __restrict__ ssoff,
                                             const float* __restrict__ dinv, const float* __restrict__ bias,
                                             float* __restrict__ O, int N) {
    int lane = threadIdx.x & 63;
    int wid = threadIdx.x >> 6;
    int sub = lane >> 3;       // 0..7: edge slot
    int l = lane & 7;          // 0..7: feature octet
    int i = blockIdx.x * 4 + wid;
    if (i >= N) return;
    const char* Gb = (const char*)G;
    int loff = l << 4;
    int beg = rowptr[i], end = rowend[i];
    float a[8] = {0.f, 0.f, 0.f, 0.f, 0.f, 0.f, 0.f, 0.f};
    int e = beg + sub;
    for (; e + 8 < end; e += 16) {
        int o0 = ssoff[e];
        int o1 = ssoff[e + 8];
        float4 g0 = *(const float4*)(Gb + o0 + loff);
        float4 g1 = *(const float4*)(Gb + o1 + loff);
        const __half2* h0 = (const __half2*)&g0;
        const __half2* h1 = (const __half2*)&g1;
        #pragma unroll
        for (int q = 0; q < 4; q++) {
            float2 f = __half22float2(__hadd2(h0[q], h1[q]));
            a[2 * q]     += f.x;
            a[2 * q + 1] += f.y;
        }
    }
    if (e < end) {
        int o0 = ssoff[e];
        float4 g0 = *(const float4*)(Gb + o0 + loff);
        const __half2* h0 = (const __half2*)&g0;
        #pragma unroll
        for (int q = 0; q < 4; q++) {
            float2 f = __half22float2(h0[q]);
            a[2 * q]     += f.x;
            a[2 * q + 1] += f.y;
        }
    }
    #pragma unroll
    for (int mask = 8; mask <= 32; mask <<= 1) {
        #pragma unroll
        for (int q = 0; q < 8; q++) a[q] += __shfl_xor(a[q], mask);
    }
    if (sub == 0) {
        float4 gs = *(const float4*)(Gb + (i << 7) + loff);
        const __half2* hs = (const __half2*)&gs;
        float di = dinv[i];
        float4 b0v = *(const float4*)(bias + 8 * l);
        float4 b1v = *(const float4*)(bias + 8 * l + 4);
        float bb[8] = {b0v.x, b0v.y, b0v.z, b0v.w, b1v.x, b1v.y, b1v.z, b1v.w};
        float r[8];
        #pragma unroll
        for (int q = 0; q < 4; q++) {
            float2 fs = __half22float2(hs[q]);
            r[2 * q]     = fmaxf(fmaf(di, a[2 * q] + fs.x, bb[2 * q]), 0.f);
            r[2 * q + 1] = fmaxf(fmaf(di, a[2 * q + 1] + fs.y, bb[2 * q + 1]), 0.f);
        }
        *(float4*)(O + (size_t)i * 64 + 8 * l)     = make_float4(r[0], r[1], r[2], r[3]);
        *(float4*)(O + (size_t)i * 64 + 8 * l + 4) = make_float4(r[4], r[5], r[6], r[7]);
    }
}

// ---------- softmax(H @ Wfc + bfc) ----------
__global__ __launch_bounds__(256) void k_fc_softmax(const float* __restrict__ H, const float* __restrict__ Wfc,
                                                    const float* __restrict__ bfc, float* __restrict__ O, int N) {
    __shared__ float wf[64 * 16];
    __shared__ float bf[16];
    int t = threadIdx.x;
    for (int k = t; k < 1024; k += 256) wf[k] = Wfc[k];
    if (t < 16) bf[t] = bfc[t];
    __syncthreads();
    int gid = blockIdx.x * 256 + t;
    int node = gid >> 4;
    int c = gid & 15;
    if (node >= N) return;
    const float4* hv = (const float4*)(H + (size_t)node * 64);
    float acc = bf[c];
    #pragma unroll
    for (int kk = 0; kk < 16; kk++) {
        float4 h4 = hv[kk];
        acc = fmaf(h4.x, wf[(4 * kk + 0) * 16 + c], acc);
        acc = fmaf(h4.y, wf[(4 * kk + 1) * 16 + c], acc);
        acc = fmaf(h4.z, wf[(4 * kk + 2) * 16 + c], acc);
        acc = fmaf(h4.w, wf[(4 * kk + 3) * 16 + c], acc);
    }
    float m = acc;
    #pragma unroll
    for (int mask = 1; mask < 16; mask <<= 1) m = fmaxf(m, __shfl_xor(m, mask));
    float ex = expf(acc - m);
    float s = ex;
    #pragma unroll
    for (int mask = 1; mask < 16; mask <<= 1) s += __shfl_xor(s, mask);
    O[(size_t)node * 16 + c] = ex / s;
}

extern "C" void kernel_launch(void* const* d_in, const int* in_sizes, int n_in,
                              void* d_out, int out_size, void* d_ws, size_t ws_size,
                              hipStream_t stream) {
    const float* x   = (const float*)d_in[0];
    const int*   ei  = (const int*)d_in[1];
    const float* W1  = (const float*)d_in[2];
    const float* b1  = (const float*)d_in[3];
    const float* W2  = (const float*)d_in[4];
    const float* b2  = (const float*)d_in[5];
    const float* Wfc = (const float*)d_in[6];
    const float* bfc = (const float*)d_in[7];
    float* out = (float*)d_out;
    const int N = NNODES;
    const int E = in_sizes[1] / 2;

    char* ws = (char*)d_ws;
    size_t off = 0;
    auto take = [&](size_t bytes) {
        char* p = ws + off;
        off = (off + bytes + 255) & ~(size_t)255;
        return p;
    };
    int*    staging = (int*)take((size_t)NBUCK * BCAP * 4);
    int*    ssoff   = (int*)take((size_t)NBUCK * BCAP * 4);
    float*  bufB    = (float*)take((size_t)N * 64 * 4);
    __half* Gh      = (__half*)take((size_t)N * 64 * 2);
    int*    rowptr  = (int*)take((size_t)N * 4);
    int*    rowend  = (int*)take((size_t)N * 4);
    float*  dinv    = (float*)take((size_t)N * 4);
    int*    bcur    = (int*)take((size_t)NBUCK * 4);

    const int* e_src = ei;
    const int* e_dst = ei + E;

    int chunk = (E + SCAT_BLOCKS - 1) / SCAT_BLOCKS;
    hipMemsetAsync(bcur, 0, (size_t)NBUCK * 4, stream);
    k_scatter_fused<<<SCAT_BLOCKS, 256, 0, stream>>>(e_src, e_dst, bcur, staging, E, chunk);
    k_csr_transform<<<NBUCK, 256, 0, stream>>>(staging, bcur, rowptr, rowend, ssoff, dinv, x, W1, Gh, N);
    k_agg<<<(N + 3) / 4, 256, 0, stream>>>(Gh, rowptr, rowend, ssoff, dinv, b1, bufB, N);
    k_transform3<<<(N + 127) / 128, 256, 0, stream>>>(bufB, W2, dinv, Gh, N);
    k_agg<<<(N + 3) / 4, 256, 0, stream>>>(Gh, rowptr, rowend, ssoff, dinv, b2, bufB, N);
    k_fc_softmax<<<(N * 16 + 255) / 256, 256, 0, stream>>>(bufB, Wfc, bfc, out, N);
}